// Round 13
// baseline (490.812 us; speedup 1.0000x reference)
//
#include <hip/hip_runtime.h>

// GCN_17377437680138: 3-layer GCN + relu + per-layer global_add_pool, concat.
// N=100000, E=1600000, F=H=64, 64 graphs, fp32 in/out.
// R10: P=4 feature-sliced layout [4][N][16] bf16 for XW/h/xbf. Gather: fg fast
// in blockIdx (XCD owns a 3.2 MB plane -> payload reads L2-hit), ONE THREAD per
// node per plane (serial edge loop, no shuffles, no atomics), csr streamed
// 4B/edge x4 planes. R8 proved the layout mechanism (FETCH collapsed) and that
// shuffles were its cost; this keeps the first, drops the second.

#define F 64
#define CAP 48
#define NRANGE 8
#define P 4           // feature planes
#define PF 16         // features per plane

typedef __attribute__((ext_vector_type(8))) short short8x;
typedef __attribute__((ext_vector_type(8))) unsigned short ushort8x;
typedef __attribute__((ext_vector_type(4))) float f32x4;

static inline size_t alignup(size_t x, size_t a) { return (x + a - 1) & ~(a - 1); }

__device__ __forceinline__ ushort f2bf(float f) {
    unsigned u = __builtin_bit_cast(unsigned, f);
    unsigned r = (u + 0x7fffu + ((u >> 16) & 1u)) >> 16;  // RNE
    return (ushort)r;
}
__device__ __forceinline__ float bf2f(ushort v) {
    return __builtin_bit_cast(float, ((unsigned)v) << 16);
}

// Dest-range-partitioned padded-CSR build (R6, unchanged).
__global__ __launch_bounds__(256) void k_build(const int* __restrict__ rowv,
                                               const int* __restrict__ colv,
                                               int* __restrict__ cnt,
                                               int* __restrict__ csr,
                                               int E, int rsize) {
    int r = blockIdx.x & (NRANGE - 1);
    int e4 = (blockIdx.x >> 3) * 256 + threadIdx.x;
    int lo = r * rsize;
    int hiEx = lo + rsize;
    int E4 = E >> 2;
    if (e4 < E4) {
        int4 c = ((const int4*)colv)[e4];
        int4 s = ((const int4*)rowv)[e4];
        int p;
        if (c.x >= lo && c.x < hiEx) {
            p = atomicAdd(&cnt[c.x], 1);
            if (p < CAP) csr[(size_t)c.x * CAP + p] = s.x;
        }
        if (c.y >= lo && c.y < hiEx) {
            p = atomicAdd(&cnt[c.y], 1);
            if (p < CAP) csr[(size_t)c.y * CAP + p] = s.y;
        }
        if (c.z >= lo && c.z < hiEx) {
            p = atomicAdd(&cnt[c.z], 1);
            if (p < CAP) csr[(size_t)c.z * CAP + p] = s.z;
        }
        if (c.w >= lo && c.w < hiEx) {
            p = atomicAdd(&cnt[c.w], 1);
            if (p < CAP) csr[(size_t)c.w * CAP + p] = s.w;
        }
    }
    int tail = E & 3;
    if (r == 0 && (int)blockIdx.x < NRANGE && (int)threadIdx.x < tail) {
        int e = (E4 << 2) + threadIdx.x;
        int c = colv[e], s = rowv[e];
        int p = atomicAdd(&cnt[c], 1);
        if (p < CAP) csr[(size_t)c * CAP + p] = s;
    }
}

// x (f32 [N][64]) -> sliced bf16 [P][N][PF]. Thread i: node=i>>2, fg=i&3.
__global__ __launch_bounds__(256) void k_prepx(const float* __restrict__ x,
                                               ushort* __restrict__ xs,
                                               int n, size_t nstride) {
    long i = (long)blockIdx.x * 256 + threadIdx.x;
    if (i >= (long)n * P) return;
    int node = (int)(i >> 2), fg = (int)(i & 3);
    ushort* o = xs + (size_t)fg * nstride + (size_t)node * PF;
#pragma unroll
    for (int c = 0; c < 4; ++c) {
        float4 v = ((const float4*)x)[(size_t)node * 16 + fg * 4 + c];
        ushort4 u;
        u.x = f2bf(v.x); u.y = f2bf(v.y); u.z = f2bf(v.z); u.w = f2bf(v.w);
        ((ushort4*)o)[c] = u;
    }
}

// W_l [64][64] f32 -> WT_l [c][k] bf16 (flat, small)
__global__ __launch_bounds__(256) void k_prepw(const float* __restrict__ W0,
                                               const float* __restrict__ W1,
                                               const float* __restrict__ W2,
                                               ushort* __restrict__ wt) {
    const float* W = (blockIdx.x == 0) ? W0 : (blockIdx.x == 1) ? W1 : W2;
    ushort* o = wt + (size_t)blockIdx.x * F * F;
    for (int i = threadIdx.x; i < F * F; i += 256) {
        int k = i >> 6, c = i & 63;
        o[c * F + k] = f2bf(W[i]);
    }
}

// MFMA GEMM, sliced in/out: XW = (H @ W) * rsqrt(deg+1).
__global__ __launch_bounds__(256) void k_gemm(const ushort* __restrict__ Hs,
                                              const ushort* __restrict__ WT,
                                              const int* __restrict__ cnt,
                                              ushort* __restrict__ XWs,
                                              int n, size_t nstride) {
    __shared__ ushort hl[64][72];
    __shared__ ushort wl[64][72];
    int rowBase = blockIdx.x * 64;
    for (int i = threadIdx.x; i < 1024; i += 256) {
        if (i < 512) {
            // i = row*8 + fg*2 + c2 : short8 chunk c2 of plane fg, row
            int row = i >> 3, fg = (i >> 1) & 3, c2 = i & 1;
            int gr = rowBase + row;
            ushort8x v = {0, 0, 0, 0, 0, 0, 0, 0};
            if (gr < n)
                v = *(const ushort8x*)(Hs + (size_t)fg * nstride + (size_t)gr * PF + c2 * 8);
            *(ushort8x*)&hl[row][fg * PF + c2 * 8] = v;
        } else {
            int idx = i & 511;
            int row = idx >> 3, cb = (idx & 7) << 3;
            *(ushort8x*)&wl[row][cb] = *(const ushort8x*)(WT + row * F + cb);
        }
    }
    __syncthreads();

    int lane = threadIdx.x & 63;
    int w = threadIdx.x >> 6;
    int l15 = lane & 15, l4 = lane >> 4;

    short8x a0 = *(const short8x*)&hl[w * 16 + l15][l4 * 8];
    short8x a1 = *(const short8x*)&hl[w * 16 + l15][32 + l4 * 8];

    f32x4 acc[4];
#pragma unroll
    for (int ct = 0; ct < 4; ++ct) {
        acc[ct] = (f32x4){0.f, 0.f, 0.f, 0.f};
        short8x b0 = *(const short8x*)&wl[ct * 16 + l15][l4 * 8];
        short8x b1 = *(const short8x*)&wl[ct * 16 + l15][32 + l4 * 8];
        acc[ct] = __builtin_amdgcn_mfma_f32_16x16x32_bf16(a0, b0, acc[ct], 0, 0, 0);
        acc[ct] = __builtin_amdgcn_mfma_f32_16x16x32_bf16(a1, b1, acc[ct], 0, 0, 0);
    }

#pragma unroll
    for (int r = 0; r < 4; ++r) {
        int gr = rowBase + w * 16 + l4 * 4 + r;
        if (gr < n) {
            float sc = rsqrtf((float)cnt[gr] + 1.0f);
            // column c = ct*16 + l15 -> plane ct, offset l15
#pragma unroll
            for (int ct = 0; ct < 4; ++ct) {
                XWs[(size_t)ct * nstride + (size_t)gr * PF + l15] = f2bf(acc[ct][r] * sc);
            }
        }
    }
}

// Sliced gather: blockIdx = chunk*4 + fg (fg fast -> XCD-local 3.2 MB plane).
// One THREAD per node: serial edge loop, 2x16B payload loads/edge (L2-hit),
// csr streamed int4. No cross-lane ops, no atomics.
__global__ __launch_bounds__(256) void k_gather(const ushort* __restrict__ XWs,
                                                const int* __restrict__ cnt,
                                                const int* __restrict__ csr,
                                                const float* __restrict__ bias,
                                                ushort* __restrict__ hs,
                                                int n, size_t nstride) {
    int fg = blockIdx.x & 3;
    int chunk = blockIdx.x >> 2;
    int node = chunk * 256 + threadIdx.x;
    if (node >= n) return;
    const ushort* plane = XWs + (size_t)fg * nstride;
    float bv[PF];
#pragma unroll
    for (int i = 0; i < PF; ++i) bv[i] = bias[fg * PF + i];

    int deg = cnt[node];
    int dmax = min(deg, CAP);
    const int* cr = csr + (size_t)node * CAP;

    float sum[PF];
    {
        ushort8x va = *(const ushort8x*)(plane + (size_t)node * PF);
        ushort8x vb = *(const ushort8x*)(plane + (size_t)node * PF + 8);
#pragma unroll
        for (int i = 0; i < 8; ++i) { sum[i] = bf2f(va[i]); sum[8 + i] = bf2f(vb[i]); }
    }
    int j = 0;
    for (; j + 4 <= dmax; j += 4) {
        int4 a = *(const int4*)(cr + j);
        ushort8x v0a = *(const ushort8x*)(plane + (size_t)a.x * PF);
        ushort8x v0b = *(const ushort8x*)(plane + (size_t)a.x * PF + 8);
        ushort8x v1a = *(const ushort8x*)(plane + (size_t)a.y * PF);
        ushort8x v1b = *(const ushort8x*)(plane + (size_t)a.y * PF + 8);
        ushort8x v2a = *(const ushort8x*)(plane + (size_t)a.z * PF);
        ushort8x v2b = *(const ushort8x*)(plane + (size_t)a.z * PF + 8);
        ushort8x v3a = *(const ushort8x*)(plane + (size_t)a.w * PF);
        ushort8x v3b = *(const ushort8x*)(plane + (size_t)a.w * PF + 8);
#pragma unroll
        for (int i = 0; i < 8; ++i) {
            sum[i] += (bf2f(v0a[i]) + bf2f(v1a[i])) + (bf2f(v2a[i]) + bf2f(v3a[i]));
            sum[8 + i] += (bf2f(v0b[i]) + bf2f(v1b[i])) + (bf2f(v2b[i]) + bf2f(v3b[i]));
        }
    }
    for (; j < dmax; ++j) {
        int src = cr[j];
        ushort8x va = *(const ushort8x*)(plane + (size_t)src * PF);
        ushort8x vb = *(const ushort8x*)(plane + (size_t)src * PF + 8);
#pragma unroll
        for (int i = 0; i < 8; ++i) { sum[i] += bf2f(va[i]); sum[8 + i] += bf2f(vb[i]); }
    }

    float sc = rsqrtf((float)deg + 1.0f);
    ushort* o = hs + (size_t)fg * nstride + (size_t)node * PF;
    ushort8x oa, ob;
#pragma unroll
    for (int i = 0; i < 8; ++i) {
        oa[i] = f2bf(fmaxf(fmaf(sum[i], sc, bv[i]), 0.f));
        ob[i] = f2bf(fmaxf(fmaf(sum[8 + i], sc, bv[8 + i]), 0.f));
    }
    *(ushort8x*)o = oa;
    *(ushort8x*)(o + 8) = ob;
}

// Per-graph pooled sum, non-atomic; reads sliced h.
__global__ __launch_bounds__(256) void k_pool(const ushort* __restrict__ hs,
                                              const int* __restrict__ batch,
                                              float* __restrict__ out,
                                              int layerOff, int n, size_t nstride) {
    __shared__ int se[2];
    __shared__ float part[4][F];
    int g = blockIdx.x;
    if (threadIdx.x == 0) {
        int lo = 0, hi = n;
        while (lo < hi) { int mid = (lo + hi) >> 1; if (batch[mid] < g) lo = mid + 1; else hi = mid; }
        se[0] = lo;
        hi = n;
        while (lo < hi) { int mid = (lo + hi) >> 1; if (batch[mid] < g + 1) lo = mid + 1; else hi = mid; }
        se[1] = lo;
    }
    __syncthreads();
    int start = se[0], end = se[1];
    int f = threadIdx.x & 63;
    int w = threadIdx.x >> 6;
    const ushort* plane = hs + (size_t)(f >> 4) * nstride + (f & 15);
    float s0 = 0.f, s1 = 0.f, s2 = 0.f, s3 = 0.f;
    int node = start + w;
    for (; node + 12 < end; node += 16) {
        s0 += bf2f(plane[(size_t)node * PF]);
        s1 += bf2f(plane[(size_t)(node + 4) * PF]);
        s2 += bf2f(plane[(size_t)(node + 8) * PF]);
        s3 += bf2f(plane[(size_t)(node + 12) * PF]);
    }
    for (; node < end; node += 4) s0 += bf2f(plane[(size_t)node * PF]);
    part[w][f] = (s0 + s1) + (s2 + s3);
    __syncthreads();
    if (threadIdx.x < F) {
        float t = part[0][f] + part[1][f] + part[2][f] + part[3][f];
        out[g * (3 * F) + layerOff + f] = t;
    }
}

extern "C" void kernel_launch(void* const* d_in, const int* in_sizes, int n_in,
                              void* d_out, int out_size, void* d_ws, size_t ws_size,
                              hipStream_t stream) {
    const float* x = (const float*)d_in[0];
    const int* edge = (const int*)d_in[1];   // [2,E]: first E = row(src), next E = col(dst)
    const int* batch = (const int*)d_in[2];
    const float* Ws[3] = {(const float*)d_in[3], (const float*)d_in[5], (const float*)d_in[7]};
    const float* bs[3] = {(const float*)d_in[4], (const float*)d_in[6], (const float*)d_in[8]};
    float* out = (float*)d_out;

    const int N = in_sizes[0] / F;
    const int E = in_sizes[1] / 2;
    const int* rowv = edge;
    const int* colv = edge + E;
    const size_t nstride = (size_t)N * PF;  // elements per plane

    // workspace layout (~58 MB)
    char* ws = (char*)d_ws;
    size_t off = 0;
    int*    cnt = (int*)(ws + off);    off = alignup(off + (size_t)N * 4, 256);
    int*    csr = (int*)(ws + off);    off = alignup(off + (size_t)N * CAP * 4, 256);
    ushort* xw  = (ushort*)(ws + off); off = alignup(off + (size_t)N * F * 2, 256);
    ushort* h   = (ushort*)(ws + off); off = alignup(off + (size_t)N * F * 2, 256);
    ushort* xbf = (ushort*)(ws + off); off = alignup(off + (size_t)N * F * 2, 256);
    ushort* wt  = (ushort*)(ws + off); off = alignup(off + (size_t)3 * F * F * 2, 256);
    (void)ws_size;

    hipMemsetAsync(cnt, 0, (size_t)N * 4, stream);

    const int rsize = (N + NRANGE - 1) / NRANGE;
    const int chunks = ((E >> 2) + 255) / 256;
    k_build<<<chunks * NRANGE, 256, 0, stream>>>(rowv, colv, cnt, csr, E, rsize);

    k_prepx<<<(int)(((long)N * P + 255) / 256), 256, 0, stream>>>(x, xbf, N, nstride);
    k_prepw<<<3, 256, 0, stream>>>(Ws[0], Ws[1], Ws[2], wt);

    const int gemmBlocks = (N + 63) / 64;
    const int gchunks = (N + 255) / 256;

    for (int l = 0; l < 3; ++l) {
        const ushort* Hin = (l == 0) ? xbf : h;
        k_gemm<<<gemmBlocks, 256, 0, stream>>>(Hin, wt + (size_t)l * F * F, cnt, xw, N, nstride);
        k_gather<<<gchunks * P, 256, 0, stream>>>(xw, cnt, csr, bs[l], h, N, nstride);
        k_pool<<<64, 256, 0, stream>>>(h, batch, out, l * F, N, nstride);
    }
}

// Round 15
// 404.197 us; speedup vs baseline: 1.2143x; 1.2143x over previous
//
#include <hip/hip_runtime.h>

// GCN_17377437680138: 3-layer GCN + relu + per-layer global_add_pool, concat.
// N=100000, E=1600000, F=H=64, 64 graphs, fp32 in/out.
// R11 (resubmit after infra failure): P=4 sliced layout [4][N][16] bf16
// (XCD-local 3.2 MB planes, R8-proven payload-L2 mechanism) + R9 lane
// discipline (4 lanes/node read the 32B row; cr int4 broadcast per 4-lane
// group -> coalesced index reads; no shuffles, no atomics).

#define F 64
#define CAP 48
#define NRANGE 8
#define P 4           // feature planes
#define PF 16         // features per plane

typedef __attribute__((ext_vector_type(8))) short short8x;
typedef __attribute__((ext_vector_type(8))) unsigned short ushort8x;
typedef __attribute__((ext_vector_type(4))) float f32x4;

static inline size_t alignup(size_t x, size_t a) { return (x + a - 1) & ~(a - 1); }

__device__ __forceinline__ ushort f2bf(float f) {
    unsigned u = __builtin_bit_cast(unsigned, f);
    unsigned r = (u + 0x7fffu + ((u >> 16) & 1u)) >> 16;  // RNE
    return (ushort)r;
}
__device__ __forceinline__ float bf2f(ushort v) {
    return __builtin_bit_cast(float, ((unsigned)v) << 16);
}

// Dest-range-partitioned padded-CSR build (R6, unchanged).
__global__ __launch_bounds__(256) void k_build(const int* __restrict__ rowv,
                                               const int* __restrict__ colv,
                                               int* __restrict__ cnt,
                                               int* __restrict__ csr,
                                               int E, int rsize) {
    int r = blockIdx.x & (NRANGE - 1);
    int e4 = (blockIdx.x >> 3) * 256 + threadIdx.x;
    int lo = r * rsize;
    int hiEx = lo + rsize;
    int E4 = E >> 2;
    if (e4 < E4) {
        int4 c = ((const int4*)colv)[e4];
        int4 s = ((const int4*)rowv)[e4];
        int p;
        if (c.x >= lo && c.x < hiEx) {
            p = atomicAdd(&cnt[c.x], 1);
            if (p < CAP) csr[(size_t)c.x * CAP + p] = s.x;
        }
        if (c.y >= lo && c.y < hiEx) {
            p = atomicAdd(&cnt[c.y], 1);
            if (p < CAP) csr[(size_t)c.y * CAP + p] = s.y;
        }
        if (c.z >= lo && c.z < hiEx) {
            p = atomicAdd(&cnt[c.z], 1);
            if (p < CAP) csr[(size_t)c.z * CAP + p] = s.z;
        }
        if (c.w >= lo && c.w < hiEx) {
            p = atomicAdd(&cnt[c.w], 1);
            if (p < CAP) csr[(size_t)c.w * CAP + p] = s.w;
        }
    }
    int tail = E & 3;
    if (r == 0 && (int)blockIdx.x < NRANGE && (int)threadIdx.x < tail) {
        int e = (E4 << 2) + threadIdx.x;
        int c = colv[e], s = rowv[e];
        int p = atomicAdd(&cnt[c], 1);
        if (p < CAP) csr[(size_t)c * CAP + p] = s;
    }
}

// x (f32 [N][64]) -> sliced bf16 [P][N][PF]. Thread i: node=i>>2, fg=i&3.
__global__ __launch_bounds__(256) void k_prepx(const float* __restrict__ x,
                                               ushort* __restrict__ xs,
                                               int n, size_t nstride) {
    long i = (long)blockIdx.x * 256 + threadIdx.x;
    if (i >= (long)n * P) return;
    int node = (int)(i >> 2), fg = (int)(i & 3);
    ushort* o = xs + (size_t)fg * nstride + (size_t)node * PF;
#pragma unroll
    for (int c = 0; c < 4; ++c) {
        float4 v = ((const float4*)x)[(size_t)node * 16 + fg * 4 + c];
        ushort4 u;
        u.x = f2bf(v.x); u.y = f2bf(v.y); u.z = f2bf(v.z); u.w = f2bf(v.w);
        ((ushort4*)o)[c] = u;
    }
}

// W_l [64][64] f32 -> WT_l [c][k] bf16
__global__ __launch_bounds__(256) void k_prepw(const float* __restrict__ W0,
                                               const float* __restrict__ W1,
                                               const float* __restrict__ W2,
                                               ushort* __restrict__ wt) {
    const float* W = (blockIdx.x == 0) ? W0 : (blockIdx.x == 1) ? W1 : W2;
    ushort* o = wt + (size_t)blockIdx.x * F * F;
    for (int i = threadIdx.x; i < F * F; i += 256) {
        int k = i >> 6, c = i & 63;
        o[c * F + k] = f2bf(W[i]);
    }
}

// MFMA GEMM, sliced in/out: XW = (H @ W) * rsqrt(deg+1).
__global__ __launch_bounds__(256) void k_gemm(const ushort* __restrict__ Hs,
                                              const ushort* __restrict__ WT,
                                              const int* __restrict__ cnt,
                                              ushort* __restrict__ XWs,
                                              int n, size_t nstride) {
    __shared__ ushort hl[64][72];
    __shared__ ushort wl[64][72];
    int rowBase = blockIdx.x * 64;
    for (int i = threadIdx.x; i < 1024; i += 256) {
        if (i < 512) {
            int row = i >> 3, fg = (i >> 1) & 3, c2 = i & 1;
            int gr = rowBase + row;
            ushort8x v = {0, 0, 0, 0, 0, 0, 0, 0};
            if (gr < n)
                v = *(const ushort8x*)(Hs + (size_t)fg * nstride + (size_t)gr * PF + c2 * 8);
            *(ushort8x*)&hl[row][fg * PF + c2 * 8] = v;
        } else {
            int idx = i & 511;
            int row = idx >> 3, cb = (idx & 7) << 3;
            *(ushort8x*)&wl[row][cb] = *(const ushort8x*)(WT + row * F + cb);
        }
    }
    __syncthreads();

    int lane = threadIdx.x & 63;
    int w = threadIdx.x >> 6;
    int l15 = lane & 15, l4 = lane >> 4;

    short8x a0 = *(const short8x*)&hl[w * 16 + l15][l4 * 8];
    short8x a1 = *(const short8x*)&hl[w * 16 + l15][32 + l4 * 8];

    f32x4 acc[4];
#pragma unroll
    for (int ct = 0; ct < 4; ++ct) {
        acc[ct] = (f32x4){0.f, 0.f, 0.f, 0.f};
        short8x b0 = *(const short8x*)&wl[ct * 16 + l15][l4 * 8];
        short8x b1 = *(const short8x*)&wl[ct * 16 + l15][32 + l4 * 8];
        acc[ct] = __builtin_amdgcn_mfma_f32_16x16x32_bf16(a0, b0, acc[ct], 0, 0, 0);
        acc[ct] = __builtin_amdgcn_mfma_f32_16x16x32_bf16(a1, b1, acc[ct], 0, 0, 0);
    }

#pragma unroll
    for (int r = 0; r < 4; ++r) {
        int gr = rowBase + w * 16 + l4 * 4 + r;
        if (gr < n) {
            float sc = rsqrtf((float)cnt[gr] + 1.0f);
#pragma unroll
            for (int ct = 0; ct < 4; ++ct) {
                XWs[(size_t)ct * nstride + (size_t)gr * PF + l15] = f2bf(acc[ct][r] * sc);
            }
        }
    }
}

// Sliced gather, R9 lane discipline: blockIdx = chunk*4 + fg (fg fast -> XCD
// plane affinity). Wave = 16 nodes (g = lane>>2) x 4 lanes (s = lane&3, one
// ushort4 = 8B; 4 lanes cover the 32B plane-row). cr int4 broadcast per group.
__global__ __launch_bounds__(256) void k_gather(const ushort* __restrict__ XWs,
                                                const int* __restrict__ cnt,
                                                const int* __restrict__ csr,
                                                const float* __restrict__ bias,
                                                ushort* __restrict__ hs,
                                                int n, size_t nstride) {
    int fg = blockIdx.x & 3;
    int chunk = blockIdx.x >> 2;
    int lane = threadIdx.x & 63;
    int w = threadIdx.x >> 6;
    int g = lane >> 2, s = lane & 3;
    int node = (chunk * 4 + w) * 16 + g;
    if (node >= n) return;

    const ushort4* rows = (const ushort4*)(XWs + (size_t)fg * nstride);
    float4 bv = ((const float4*)bias)[fg * 4 + s];

    int deg = cnt[node];
    int dmax = min(deg, CAP);
    const int* cr = csr + (size_t)node * CAP;

    float4 sum;
    {
        ushort4 v = rows[(size_t)node * 4 + s];  // self loop (dinv folded in XW)
        sum = make_float4(bf2f(v.x), bf2f(v.y), bf2f(v.z), bf2f(v.w));
    }
    int j = 0;
    for (; j + 4 <= dmax; j += 4) {
        int4 a = *(const int4*)(cr + j);  // broadcast within the 4-lane group
        ushort4 v0 = rows[(size_t)a.x * 4 + s];
        ushort4 v1 = rows[(size_t)a.y * 4 + s];
        ushort4 v2 = rows[(size_t)a.z * 4 + s];
        ushort4 v3 = rows[(size_t)a.w * 4 + s];
        sum.x += (bf2f(v0.x) + bf2f(v1.x)) + (bf2f(v2.x) + bf2f(v3.x));
        sum.y += (bf2f(v0.y) + bf2f(v1.y)) + (bf2f(v2.y) + bf2f(v3.y));
        sum.z += (bf2f(v0.z) + bf2f(v1.z)) + (bf2f(v2.z) + bf2f(v3.z));
        sum.w += (bf2f(v0.w) + bf2f(v1.w)) + (bf2f(v2.w) + bf2f(v3.w));
    }
    for (; j < dmax; ++j) {
        ushort4 v = rows[(size_t)cr[j] * 4 + s];
        sum.x += bf2f(v.x); sum.y += bf2f(v.y);
        sum.z += bf2f(v.z); sum.w += bf2f(v.w);
    }

    float sc = rsqrtf((float)deg + 1.0f);
    ushort4 o;
    o.x = f2bf(fmaxf(fmaf(sum.x, sc, bv.x), 0.f));
    o.y = f2bf(fmaxf(fmaf(sum.y, sc, bv.y), 0.f));
    o.z = f2bf(fmaxf(fmaf(sum.z, sc, bv.z), 0.f));
    o.w = f2bf(fmaxf(fmaf(sum.w, sc, bv.w), 0.f));
    ((ushort4*)(hs + (size_t)fg * nstride))[(size_t)node * 4 + s] = o;
}

// Per-graph pooled sum, non-atomic; reads sliced h.
__global__ __launch_bounds__(256) void k_pool(const ushort* __restrict__ hs,
                                              const int* __restrict__ batch,
                                              float* __restrict__ out,
                                              int layerOff, int n, size_t nstride) {
    __shared__ int se[2];
    __shared__ float part[4][F];
    int g = blockIdx.x;
    if (threadIdx.x == 0) {
        int lo = 0, hi = n;
        while (lo < hi) { int mid = (lo + hi) >> 1; if (batch[mid] < g) lo = mid + 1; else hi = mid; }
        se[0] = lo;
        hi = n;
        while (lo < hi) { int mid = (lo + hi) >> 1; if (batch[mid] < g + 1) lo = mid + 1; else hi = mid; }
        se[1] = lo;
    }
    __syncthreads();
    int start = se[0], end = se[1];
    int f = threadIdx.x & 63;
    int w = threadIdx.x >> 6;
    const ushort* plane = hs + (size_t)(f >> 4) * nstride + (f & 15);
    float s0 = 0.f, s1 = 0.f, s2 = 0.f, s3 = 0.f;
    int node = start + w;
    for (; node + 12 < end; node += 16) {
        s0 += bf2f(plane[(size_t)node * PF]);
        s1 += bf2f(plane[(size_t)(node + 4) * PF]);
        s2 += bf2f(plane[(size_t)(node + 8) * PF]);
        s3 += bf2f(plane[(size_t)(node + 12) * PF]);
    }
    for (; node < end; node += 4) s0 += bf2f(plane[(size_t)node * PF]);
    part[w][f] = (s0 + s1) + (s2 + s3);
    __syncthreads();
    if (threadIdx.x < F) {
        float t = part[0][f] + part[1][f] + part[2][f] + part[3][f];
        out[g * (3 * F) + layerOff + f] = t;
    }
}

extern "C" void kernel_launch(void* const* d_in, const int* in_sizes, int n_in,
                              void* d_out, int out_size, void* d_ws, size_t ws_size,
                              hipStream_t stream) {
    const float* x = (const float*)d_in[0];
    const int* edge = (const int*)d_in[1];   // [2,E]: first E = row(src), next E = col(dst)
    const int* batch = (const int*)d_in[2];
    const float* Ws[3] = {(const float*)d_in[3], (const float*)d_in[5], (const float*)d_in[7]};
    const float* bs[3] = {(const float*)d_in[4], (const float*)d_in[6], (const float*)d_in[8]};
    float* out = (float*)d_out;

    const int N = in_sizes[0] / F;
    const int E = in_sizes[1] / 2;
    const int* rowv = edge;
    const int* colv = edge + E;
    const size_t nstride = (size_t)N * PF;  // elements per plane

    // workspace layout (~58 MB)
    char* ws = (char*)d_ws;
    size_t off = 0;
    int*    cnt = (int*)(ws + off);    off = alignup(off + (size_t)N * 4, 256);
    int*    csr = (int*)(ws + off);    off = alignup(off + (size_t)N * CAP * 4, 256);
    ushort* xw  = (ushort*)(ws + off); off = alignup(off + (size_t)N * F * 2, 256);
    ushort* h   = (ushort*)(ws + off); off = alignup(off + (size_t)N * F * 2, 256);
    ushort* xbf = (ushort*)(ws + off); off = alignup(off + (size_t)N * F * 2, 256);
    ushort* wt  = (ushort*)(ws + off); off = alignup(off + (size_t)3 * F * F * 2, 256);
    (void)ws_size;

    hipMemsetAsync(cnt, 0, (size_t)N * 4, stream);

    const int rsize = (N + NRANGE - 1) / NRANGE;
    const int chunks = ((E >> 2) + 255) / 256;
    k_build<<<chunks * NRANGE, 256, 0, stream>>>(rowv, colv, cnt, csr, E, rsize);

    k_prepx<<<(int)(((long)N * P + 255) / 256), 256, 0, stream>>>(x, xbf, N, nstride);
    k_prepw<<<3, 256, 0, stream>>>(Ws[0], Ws[1], Ws[2], wt);

    const int gemmBlocks = (N + 63) / 64;
    const int gchunks = (N + 63) / 64;  // 64 nodes per block (4 waves x 16)

    for (int l = 0; l < 3; ++l) {
        const ushort* Hin = (l == 0) ? xbf : h;
        k_gemm<<<gemmBlocks, 256, 0, stream>>>(Hin, wt + (size_t)l * F * F, cnt, xw, N, nstride);
        k_gather<<<gchunks * P, 256, 0, stream>>>(xw, cnt, csr, bs[l], h, N, nstride);
        k_pool<<<64, 256, 0, stream>>>(h, batch, out, l * F, N, nstride);
    }
}

// Round 17
// 318.532 us; speedup vs baseline: 1.5409x; 1.2689x over previous
//
#include <hip/hip_runtime.h>

// GCN_17377437680138: 3-layer GCN + relu + per-layer global_add_pool, concat.
// N=100000, E=1600000, F=H=64, 64 graphs, fp32 in/out.
// R12 (resubmit after infra failure): R9 baseline (flat bf16, MFMA GEMM,
// range-partitioned build) + pool fused into gather via LDS bins (batch sorted
// -> block spans few graphs; ~(span+1)*64 global atomics per block) + layer-3
// h-write skipped.

#define F 64
#define CAP 48
#define NRANGE 8

typedef __attribute__((ext_vector_type(8))) short short8x;
typedef __attribute__((ext_vector_type(8))) unsigned short ushort8x;
typedef __attribute__((ext_vector_type(4))) float f32x4;

static inline size_t alignup(size_t x, size_t a) { return (x + a - 1) & ~(a - 1); }

__device__ __forceinline__ ushort f2bf(float f) {
    unsigned u = __builtin_bit_cast(unsigned, f);
    unsigned r = (u + 0x7fffu + ((u >> 16) & 1u)) >> 16;  // RNE
    return (ushort)r;
}
__device__ __forceinline__ float bf2f(ushort v) {
    return __builtin_bit_cast(float, ((unsigned)v) << 16);
}

// Dest-range-partitioned padded-CSR build (R6, unchanged).
__global__ __launch_bounds__(256) void k_build(const int* __restrict__ rowv,
                                               const int* __restrict__ colv,
                                               int* __restrict__ cnt,
                                               int* __restrict__ csr,
                                               int E, int rsize) {
    int r = blockIdx.x & (NRANGE - 1);
    int e4 = (blockIdx.x >> 3) * 256 + threadIdx.x;
    int lo = r * rsize;
    int hiEx = lo + rsize;
    int E4 = E >> 2;
    if (e4 < E4) {
        int4 c = ((const int4*)colv)[e4];
        int4 s = ((const int4*)rowv)[e4];
        int p;
        if (c.x >= lo && c.x < hiEx) {
            p = atomicAdd(&cnt[c.x], 1);
            if (p < CAP) csr[(size_t)c.x * CAP + p] = s.x;
        }
        if (c.y >= lo && c.y < hiEx) {
            p = atomicAdd(&cnt[c.y], 1);
            if (p < CAP) csr[(size_t)c.y * CAP + p] = s.y;
        }
        if (c.z >= lo && c.z < hiEx) {
            p = atomicAdd(&cnt[c.z], 1);
            if (p < CAP) csr[(size_t)c.z * CAP + p] = s.z;
        }
        if (c.w >= lo && c.w < hiEx) {
            p = atomicAdd(&cnt[c.w], 1);
            if (p < CAP) csr[(size_t)c.w * CAP + p] = s.w;
        }
    }
    int tail = E & 3;
    if (r == 0 && (int)blockIdx.x < NRANGE && (int)threadIdx.x < tail) {
        int e = (E4 << 2) + threadIdx.x;
        int c = colv[e], s = rowv[e];
        int p = atomicAdd(&cnt[c], 1);
        if (p < CAP) csr[(size_t)c * CAP + p] = s;
    }
}

// x (f32) -> bf16 flat
__global__ __launch_bounds__(256) void k_prepx(const float* __restrict__ x,
                                               ushort* __restrict__ xbf, long n4) {
    long i = (long)blockIdx.x * 256 + threadIdx.x;
    if (i < n4) {
        float4 v = ((const float4*)x)[i];
        ushort4 u;
        u.x = f2bf(v.x); u.y = f2bf(v.y); u.z = f2bf(v.z); u.w = f2bf(v.w);
        ((ushort4*)xbf)[i] = u;
    }
}

// W_l [64][64] f32 -> WT_l [c][k] bf16
__global__ __launch_bounds__(256) void k_prepw(const float* __restrict__ W0,
                                               const float* __restrict__ W1,
                                               const float* __restrict__ W2,
                                               ushort* __restrict__ wt) {
    const float* W = (blockIdx.x == 0) ? W0 : (blockIdx.x == 1) ? W1 : W2;
    ushort* o = wt + (size_t)blockIdx.x * F * F;
    for (int i = threadIdx.x; i < F * F; i += 256) {
        int k = i >> 6, c = i & 63;
        o[c * F + k] = f2bf(W[i]);
    }
}

// MFMA GEMM (R7): XW[r][c] = (sum_k Hbf[r][k] * W[k][c]) * rsqrt(deg[r]+1), bf16.
__global__ __launch_bounds__(256) void k_gemm(const ushort* __restrict__ Hbf,
                                              const ushort* __restrict__ WT,
                                              const int* __restrict__ cnt,
                                              ushort* __restrict__ XW, int n) {
    __shared__ ushort hl[64][72];
    __shared__ ushort wl[64][72];
    int rowBase = blockIdx.x * 64;
    for (int i = threadIdx.x; i < 1024; i += 256) {
        int idx = i & 511;
        int row = idx >> 3, cb = (idx & 7) << 3;
        if (i < 512) {
            int gr = rowBase + row;
            short8x v = {0, 0, 0, 0, 0, 0, 0, 0};
            if (gr < n) v = *(const short8x*)(Hbf + (size_t)gr * F + cb);
            *(short8x*)&hl[row][cb] = v;
        } else {
            *(short8x*)&wl[row][cb] = *(const short8x*)(WT + row * F + cb);
        }
    }
    __syncthreads();

    int lane = threadIdx.x & 63;
    int w = threadIdx.x >> 6;
    int l15 = lane & 15, l4 = lane >> 4;

    short8x a0 = *(const short8x*)&hl[w * 16 + l15][l4 * 8];
    short8x a1 = *(const short8x*)&hl[w * 16 + l15][32 + l4 * 8];

    f32x4 acc[4];
#pragma unroll
    for (int ct = 0; ct < 4; ++ct) {
        acc[ct] = (f32x4){0.f, 0.f, 0.f, 0.f};
        short8x b0 = *(const short8x*)&wl[ct * 16 + l15][l4 * 8];
        short8x b1 = *(const short8x*)&wl[ct * 16 + l15][32 + l4 * 8];
        acc[ct] = __builtin_amdgcn_mfma_f32_16x16x32_bf16(a0, b0, acc[ct], 0, 0, 0);
        acc[ct] = __builtin_amdgcn_mfma_f32_16x16x32_bf16(a1, b1, acc[ct], 0, 0, 0);
    }

#pragma unroll
    for (int r = 0; r < 4; ++r) {
        int gr = rowBase + w * 16 + l4 * 4 + r;
        if (gr < n) {
            float sc = rsqrtf((float)cnt[gr] + 1.0f);
#pragma unroll
            for (int ct = 0; ct < 4; ++ct) {
                XW[(size_t)gr * F + ct * 16 + l15] = f2bf(acc[ct][r] * sc);
            }
        }
    }
}

// Gather + fused pool. Block = 4 waves x 8 nodes = 32 consecutive nodes.
// Lane: q = lane>>3 (node slot), s = lane&7 (feature octet, ushort8 16B loads).
// Pool: LDS bins[32][64] indexed by batch[node]-batch[blockStart] (batch
// sorted -> index in [0,31]); flushed with (bspan+1)*64 global atomics.
__global__ __launch_bounds__(256) void k_gather(const ushort* __restrict__ XW,
                                                const int* __restrict__ cnt,
                                                const int* __restrict__ csr,
                                                const float* __restrict__ bias,
                                                const int* __restrict__ batch,
                                                ushort* __restrict__ h,
                                                float* __restrict__ out,
                                                int layerOff, int n, int writeH) {
    __shared__ float bins[32][F];
    __shared__ int binfo[2];  // b0, bspan
    for (int i = threadIdx.x; i < 32 * F; i += 256) ((float*)bins)[i] = 0.f;
    int blockStart = blockIdx.x * 32;
    if (threadIdx.x == 0) {
        int b0 = batch[min(blockStart, n - 1)];
        int bl = batch[min(blockStart + 31, n - 1)];
        binfo[0] = b0;
        binfo[1] = bl - b0;
    }
    __syncthreads();

    int lane = threadIdx.x & 63;
    int q = lane >> 3, s = lane & 7;
    int wave = threadIdx.x >> 6;
    int node = blockStart + wave * 8 + q;

    if (node < n) {
        float4 bv0 = ((const float4*)bias)[s * 2];
        float4 bv1 = ((const float4*)bias)[s * 2 + 1];

        int deg = cnt[node];
        int dmax = min(deg, CAP);
        const int* cr = csr + (size_t)node * CAP;
        const ushort8x* rows = (const ushort8x*)XW;

        float sum[8];
        {
            ushort8x v = rows[(size_t)node * 8 + s];  // self loop (dinv folded in XW)
#pragma unroll
            for (int i = 0; i < 8; ++i) sum[i] = bf2f(v[i]);
        }
        int j = 0;
        for (; j + 4 <= dmax; j += 4) {
            int4 a = *(const int4*)(cr + j);
            ushort8x v0 = rows[(size_t)a.x * 8 + s];
            ushort8x v1 = rows[(size_t)a.y * 8 + s];
            ushort8x v2 = rows[(size_t)a.z * 8 + s];
            ushort8x v3 = rows[(size_t)a.w * 8 + s];
#pragma unroll
            for (int i = 0; i < 8; ++i)
                sum[i] += (bf2f(v0[i]) + bf2f(v1[i])) + (bf2f(v2[i]) + bf2f(v3[i]));
        }
        for (; j < dmax; ++j) {
            ushort8x v = rows[(size_t)cr[j] * 8 + s];
#pragma unroll
            for (int i = 0; i < 8; ++i) sum[i] += bf2f(v[i]);
        }

        float sc = rsqrtf((float)deg + 1.0f);
        float val[8];
        val[0] = fmaxf(fmaf(sum[0], sc, bv0.x), 0.f);
        val[1] = fmaxf(fmaf(sum[1], sc, bv0.y), 0.f);
        val[2] = fmaxf(fmaf(sum[2], sc, bv0.z), 0.f);
        val[3] = fmaxf(fmaf(sum[3], sc, bv0.w), 0.f);
        val[4] = fmaxf(fmaf(sum[4], sc, bv1.x), 0.f);
        val[5] = fmaxf(fmaf(sum[5], sc, bv1.y), 0.f);
        val[6] = fmaxf(fmaf(sum[6], sc, bv1.z), 0.f);
        val[7] = fmaxf(fmaf(sum[7], sc, bv1.w), 0.f);

        if (writeH) {
            ushort8x o;
#pragma unroll
            for (int i = 0; i < 8; ++i) o[i] = f2bf(val[i]);
            ((ushort8x*)h)[(size_t)node * 8 + s] = o;
        }

        int k = batch[node] - binfo[0];
        float* bin = &bins[k][s * 8];
#pragma unroll
        for (int i = 0; i < 8; ++i) atomicAdd(&bin[i], val[i]);
    }
    __syncthreads();

    int b0 = binfo[0], bspan = binfo[1];
    for (int k = 0; k <= bspan; ++k) {
        if (threadIdx.x < F) {
            atomicAdd(&out[(b0 + k) * (3 * F) + layerOff + threadIdx.x],
                      bins[k][threadIdx.x]);
        }
    }
}

extern "C" void kernel_launch(void* const* d_in, const int* in_sizes, int n_in,
                              void* d_out, int out_size, void* d_ws, size_t ws_size,
                              hipStream_t stream) {
    const float* x = (const float*)d_in[0];
    const int* edge = (const int*)d_in[1];   // [2,E]: first E = row(src), next E = col(dst)
    const int* batch = (const int*)d_in[2];
    const float* Ws[3] = {(const float*)d_in[3], (const float*)d_in[5], (const float*)d_in[7]};
    const float* bs[3] = {(const float*)d_in[4], (const float*)d_in[6], (const float*)d_in[8]};
    float* out = (float*)d_out;

    const int N = in_sizes[0] / F;
    const int E = in_sizes[1] / 2;
    const int* rowv = edge;
    const int* colv = edge + E;

    // workspace layout (~58 MB)
    char* ws = (char*)d_ws;
    size_t off = 0;
    int*    cnt = (int*)(ws + off);    off = alignup(off + (size_t)N * 4, 256);
    int*    csr = (int*)(ws + off);    off = alignup(off + (size_t)N * CAP * 4, 256);
    ushort* xw  = (ushort*)(ws + off); off = alignup(off + (size_t)N * F * 2, 256);
    ushort* h   = (ushort*)(ws + off); off = alignup(off + (size_t)N * F * 2, 256);
    ushort* xbf = (ushort*)(ws + off); off = alignup(off + (size_t)N * F * 2, 256);
    ushort* wt  = (ushort*)(ws + off); off = alignup(off + (size_t)3 * F * F * 2, 256);
    (void)ws_size;

    hipMemsetAsync(out, 0, (size_t)out_size * sizeof(float), stream);
    hipMemsetAsync(cnt, 0, (size_t)N * 4, stream);

    const int rsize = (N + NRANGE - 1) / NRANGE;
    const int chunks = ((E >> 2) + 255) / 256;
    k_build<<<chunks * NRANGE, 256, 0, stream>>>(rowv, colv, cnt, csr, E, rsize);

    const long n4 = ((long)N * F) / 4;
    k_prepx<<<(int)((n4 + 255) / 256), 256, 0, stream>>>(x, xbf, n4);
    k_prepw<<<3, 256, 0, stream>>>(Ws[0], Ws[1], Ws[2], wt);

    const int gemmBlocks = (N + 63) / 64;
    const int gatherBlocks = (N + 31) / 32;

    for (int l = 0; l < 3; ++l) {
        const ushort* Hin = (l == 0) ? xbf : h;
        k_gemm<<<gemmBlocks, 256, 0, stream>>>(Hin, wt + (size_t)l * F * F, cnt, xw, N);
        k_gather<<<gatherBlocks, 256, 0, stream>>>(xw, cnt, csr, bs[l], batch, h, out,
                                                   l * F, N, (l < 2) ? 1 : 0);
    }
}